// Round 13
// baseline (426.065 us; speedup 1.0000x reference)
//
#include <hip/hip_runtime.h>
#include <math.h>

#define NNODES 50000
#define NEDGES 800000
#define NTOT   850000   // edges + self-loops
#define NHEAD  8
#define HDIM   32
#define HHD    256      // NHEAD*HDIM
#define NCLS   40
#define NEG_SLOPE 0.2f

typedef _Float16 half4 __attribute__((ext_vector_type(4)));
typedef _Float16 half8 __attribute__((ext_vector_type(8)));
typedef float f32x16 __attribute__((ext_vector_type(16)));
typedef unsigned short u16;

// ---------------- CSR build ----------------

__global__ void k_init_counts(int* __restrict__ counts) {
    int i = blockIdx.x * 256 + threadIdx.x;
    if (i < NNODES) counts[i] = 1;   // self-loop
}

__global__ void k_count(const int* __restrict__ ei, int* __restrict__ counts) {
    int i = blockIdx.x * 256 + threadIdx.x;
    if (i < NEDGES) atomicAdd(&counts[ei[NEDGES + i]], 1);  // dst row
}

__global__ __launch_bounds__(256) void k_scan1(const int* __restrict__ counts,
                                               int* __restrict__ partial,
                                               int* __restrict__ bsums) {
    __shared__ int lds[256];
    int t = threadIdx.x;
    int i = blockIdx.x * 256 + t;
    int v = (i < NNODES) ? counts[i] : 0;
    lds[t] = v;
    __syncthreads();
    for (int off = 1; off < 256; off <<= 1) {
        int add = (t >= off) ? lds[t - off] : 0;
        __syncthreads();
        lds[t] += add;
        __syncthreads();
    }
    if (i < NNODES) partial[i] = lds[t] - v;   // exclusive within block
    if (t == 255) bsums[blockIdx.x] = lds[255];
}

__global__ __launch_bounds__(256) void k_scan2(const int* __restrict__ bsums,
                                               int* __restrict__ boff, int nb) {
    __shared__ int lds[256];
    int t = threadIdx.x;
    int v = (t < nb) ? bsums[t] : 0;
    lds[t] = v;
    __syncthreads();
    for (int off = 1; off < 256; off <<= 1) {
        int add = (t >= off) ? lds[t - off] : 0;
        __syncthreads();
        lds[t] += add;
        __syncthreads();
    }
    if (t < nb) boff[t] = lds[t] - v;
}

__global__ void k_scan3(int* __restrict__ row_ptr, const int* __restrict__ boff,
                        int* __restrict__ cursor) {
    int i = blockIdx.x * 256 + threadIdx.x;
    if (i < NNODES) {
        int r = row_ptr[i] + boff[blockIdx.x];
        row_ptr[i] = r;
        cursor[i] = r;
    }
    if (i == 0) row_ptr[NNODES] = NTOT;
}

// fused: regular edges + self-loops
__global__ void k_scatter(const int* __restrict__ ei, int* __restrict__ cursor,
                          int* __restrict__ esrc) {
    int i = blockIdx.x * 256 + threadIdx.x;
    if (i < NEDGES) {
        int s = ei[i];
        int d = ei[NEDGES + i];
        int pos = atomicAdd(&cursor[d], 1);
        esrc[pos] = s;
    } else if (i < NTOT) {
        int n = i - NEDGES;
        int pos = atomicAdd(&cursor[n], 1);
        esrc[pos] = n;
    }
}

// ---------------- weight prep ----------------
// W1/W2 -> MFMA fragment layout (frag f=(fn,fk); lane l holds 8 halves of
// col n=fn*32+(l&31), rows k=fk*16+((l>>5)<<3)+j; 1 KB contiguous per frag).
// Wc -> WcT[40][256] fp16 (class-major rows for the fused classifier).
__global__ void k_prep_all(const float* __restrict__ W1, const float* __restrict__ W2,
                           const float* __restrict__ Wc,
                           _Float16* __restrict__ w1t, _Float16* __restrict__ w2t,
                           _Float16* __restrict__ wcT) {
    int gid = blockIdx.x * 256 + threadIdx.x;
    if (gid < 192 * 64) {
        int frag = gid >> 6, l = gid & 63;
        const float* W; _Float16* Wt; int K, fkn, fbase;
        if (frag < 64) { W = W1; Wt = w1t; K = 128; fkn = 8;  fbase = 0; }
        else           { W = W2; Wt = w2t; K = 256; fkn = 16; fbase = 64; }
        int f = frag - fbase;
        int fn = f / fkn, fk = f - fn * fkn;
        int n = fn * 32 + (l & 31);
        int k = fk * 16 + ((l >> 5) << 3);
        half8 v;
        #pragma unroll
        for (int j = 0; j < 8; ++j)
            v[j] = (_Float16)W[(size_t)(k + j) * HHD + n];
        *reinterpret_cast<half8*>(Wt + ((size_t)f * 64 + l) * 8) = v;
    } else {
        int idx = gid - 192 * 64;
        if (idx < NCLS * HHD) {
            int c = idx >> 8, k = idx & 255;
            wcT[idx] = (_Float16)Wc[(size_t)k * NCLS + c];
        }
    }
}

// ---------------- MFMA f16 GEMM + LDS-staged alpha epilogue (R9 form) ------
// Epilogue stores the fp16 C tile to LDS Ct, then 512 (row,head) dots of 32
// compute alpha_s/alpha_d (head = blockIdx.x*4 + (col>>5)). Known-good.
#define TBM 128
#define TBN 128
#define TBK 32
#define APAD 34   // 68 B row stride = 17 banks (odd) -> conflict-free b128

template <typename AT>
__global__ __launch_bounds__(256) void k_mfma_gemm(
    const AT* __restrict__ A,
    const _Float16* __restrict__ Wt,   // fragment-packed
    _Float16* __restrict__ Ch,
    const float* __restrict__ a_src,   // [8][32]
    const float* __restrict__ a_dst,
    float* __restrict__ alpha_s,       // [N][8]
    float* __restrict__ alpha_d,
    int M, int K, int ldc)
{
    constexpr bool A_IS_F32 = sizeof(AT) == 4;
    __shared__ _Float16 Ah[TBM][APAD];
    __shared__ _Float16 Ct[TBM][TBN + 4];
    int t = threadIdx.x;
    int lane = t & 63;
    int wid = t >> 6;
    int wr = wid >> 1, wc = wid & 1;            // 2x2 wave grid
    int rowBase = blockIdx.y * TBM;
    int colBase = blockIdx.x * TBN;

    int arow = t >> 1;
    int akoff = (t & 1) * 16;
    bool arow_ok = (rowBase + arow) < M;
    const AT* aptr = A + (size_t)(rowBase + arow) * K + akoff;

    int fkn = K >> 4;   // frags per n-tile row
    size_t bbase[2];
    #pragma unroll
    for (int ct = 0; ct < 2; ++ct) {
        int fn = blockIdx.x * 4 + wc * 2 + ct;
        bbase[ct] = ((size_t)fn * fkn) * 512 + (size_t)lane * 8;
    }

    f32x16 acc[2][2];
    #pragma unroll
    for (int i = 0; i < 2; ++i)
        #pragma unroll
        for (int j = 0; j < 2; ++j)
            #pragma unroll
            for (int r = 0; r < 16; ++r) acc[i][j][r] = 0.f;

    float4 aregf[4];
    half8  aregh[2];
    auto load_a = [&](const AT* ap) {
        if constexpr (A_IS_F32) {
            #pragma unroll
            for (int i = 0; i < 4; ++i)
                aregf[i] = arow_ok ? *reinterpret_cast<const float4*>((const float*)ap + i * 4)
                                   : float4{0.f, 0.f, 0.f, 0.f};
        } else {
            #pragma unroll
            for (int i = 0; i < 2; ++i)
                aregh[i] = arow_ok ? *reinterpret_cast<const half8*>((const _Float16*)ap + i * 8)
                                   : half8{0, 0, 0, 0, 0, 0, 0, 0};
        }
    };
    load_a(aptr);

    for (int k0 = 0; k0 < K; k0 += TBK) {
        if constexpr (A_IS_F32) {
            half8 h0, h1;
            #pragma unroll
            for (int c = 0; c < 4; ++c) {
                float4 v = aregf[c];
                if (c < 2) {
                    h0[c * 4 + 0] = (_Float16)v.x; h0[c * 4 + 1] = (_Float16)v.y;
                    h0[c * 4 + 2] = (_Float16)v.z; h0[c * 4 + 3] = (_Float16)v.w;
                } else {
                    h1[(c - 2) * 4 + 0] = (_Float16)v.x; h1[(c - 2) * 4 + 1] = (_Float16)v.y;
                    h1[(c - 2) * 4 + 2] = (_Float16)v.z; h1[(c - 2) * 4 + 3] = (_Float16)v.w;
                }
            }
            *reinterpret_cast<half8*>(&Ah[arow][akoff])     = h0;
            *reinterpret_cast<half8*>(&Ah[arow][akoff + 8]) = h1;
        } else {
            *reinterpret_cast<half8*>(&Ah[arow][akoff])     = aregh[0];
            *reinterpret_cast<half8*>(&Ah[arow][akoff + 8]) = aregh[1];
        }
        __syncthreads();
        if (k0 + TBK < K) load_a(aptr + k0 + TBK);
        #pragma unroll
        for (int sub = 0; sub < 2; ++sub) {
            int kfo = sub * 16 + (lane >> 5) * 8;
            half8 ah[2];
            #pragma unroll
            for (int rt = 0; rt < 2; ++rt) {
                int r = wr * 64 + rt * 32 + (lane & 31);
                ah[rt] = *reinterpret_cast<const half8*>(&Ah[r][kfo]);
            }
            half8 bh[2];
            int fidx = (k0 >> 4) + sub;            // fragment k index
            #pragma unroll
            for (int ct = 0; ct < 2; ++ct)
                bh[ct] = *reinterpret_cast<const half8*>(Wt + bbase[ct] + (size_t)fidx * 512);
            #pragma unroll
            for (int rt = 0; rt < 2; ++rt)
                #pragma unroll
                for (int ct = 0; ct < 2; ++ct)
                    acc[rt][ct] = __builtin_amdgcn_mfma_f32_32x32x16_f16(
                        ah[rt], bh[ct], acc[rt][ct], 0, 0, 0);
        }
        __syncthreads();
    }

    // ---- C store + LDS stage: col=lane&31, row=(r&3)+8*(r>>2)+4*(lane>>5) --
    #pragma unroll
    for (int rt = 0; rt < 2; ++rt)
        #pragma unroll
        for (int ct = 0; ct < 2; ++ct) {
            int lcol = wc * 64 + ct * 32 + (lane & 31);
            int col = colBase + lcol;
            #pragma unroll
            for (int r = 0; r < 16; ++r) {
                int lrow = wr * 64 + rt * 32 + (r & 3) + 8 * (r >> 2) + 4 * (lane >> 5);
                int row = rowBase + lrow;
                _Float16 hv = (_Float16)acc[rt][ct][r];
                Ct[lrow][lcol] = hv;
                if (row < M)
                    Ch[(size_t)row * ldc + col] = hv;
            }
        }

    __syncthreads();
    // 128 rows x 4 heads = 512 (row, head) pairs; 2 per thread
    #pragma unroll
    for (int idx = t; idx < TBM * 4; idx += 256) {
        int lrow = idx >> 2, hoff = idx & 3;
        int grow = rowBase + lrow;
        if (grow < M) {
            int h = blockIdx.x * 4 + hoff;
            const float* as4 = a_src + h * HDIM;
            const float* ad4 = a_dst + h * HDIM;
            float ss = 0.f, sd = 0.f;
            #pragma unroll
            for (int j = 0; j < HDIM; ++j) {
                float v = (float)Ct[lrow][hoff * 32 + j];
                ss += v * as4[j];
                sd += v * ad4[j];
            }
            alpha_s[grow * NHEAD + h] = ss;
            alpha_d[grow * NHEAD + h] = sd;
        }
    }
}

// ---------------- GAT aggregation (+ LDS-mediated fused classifier) --------
// 2 nodes per wave; lane l in [0,32) covers dims [8l, 8l+8) via one half8.
// FUSE_CLS: store the 8 ReLU'd node rows to LDS (4 KB), one barrier (safe:
// NNODES % 8 == 0 -> no early returns), then 320 (node,class) dots of 256
// across the block's threads. No per-lane class array -> VGPR stays low.
template <bool FUSE_CLS>
__global__ __launch_bounds__(256) void k_agg(const _Float16* __restrict__ xh,
                                             const float* __restrict__ alpha_s,
                                             const float* __restrict__ alpha_d,
                                             const int* __restrict__ row_ptr,
                                             const int* __restrict__ esrc,
                                             const float* __restrict__ bias,
                                             _Float16* __restrict__ out_h,
                                             const _Float16* __restrict__ WcT,
                                             const float* __restrict__ bc,
                                             float* __restrict__ out_f) {
    __shared__ _Float16 sh[FUSE_CLS ? 8 : 1][HHD];
    int wave = blockIdx.x * 4 + (threadIdx.x >> 6);
    int node = wave * 2 + ((threadIdx.x & 63) >> 5);
    // NNODES % 8 == 0: node < NNODES always; no early return (barrier-safe).
    int l = threadIdx.x & 31;        // dim chunk [8l, 8l+8)
    int h = l >> 2;                  // head of this chunk
    int beg = row_ptr[node], end = row_ptr[node + 1];
    float ad = alpha_d[node * NHEAD + h];
    float acc[8] = {};
    float ssum = 0.f;
    int i = beg;
    for (; i + 3 < end; i += 4) {
        int s0 = esrc[i], s1 = esrc[i + 1], s2 = esrc[i + 2], s3 = esrc[i + 3];
        float e0 = alpha_s[s0 * NHEAD + h] + ad;
        float e1 = alpha_s[s1 * NHEAD + h] + ad;
        float e2 = alpha_s[s2 * NHEAD + h] + ad;
        float e3 = alpha_s[s3 * NHEAD + h] + ad;
        half8 v0 = *reinterpret_cast<const half8*>(xh + (size_t)s0 * HHD + l * 8);
        half8 v1 = *reinterpret_cast<const half8*>(xh + (size_t)s1 * HHD + l * 8);
        half8 v2 = *reinterpret_cast<const half8*>(xh + (size_t)s2 * HHD + l * 8);
        half8 v3 = *reinterpret_cast<const half8*>(xh + (size_t)s3 * HHD + l * 8);
        e0 = (e0 > 0.f) ? e0 : NEG_SLOPE * e0;
        e1 = (e1 > 0.f) ? e1 : NEG_SLOPE * e1;
        e2 = (e2 > 0.f) ? e2 : NEG_SLOPE * e2;
        e3 = (e3 > 0.f) ? e3 : NEG_SLOPE * e3;
        float p0 = __expf(e0), p1 = __expf(e1), p2 = __expf(e2), p3 = __expf(e3);
        ssum += (p0 + p1) + (p2 + p3);
        #pragma unroll
        for (int d = 0; d < 8; ++d)
            acc[d] += p0 * (float)v0[d] + p1 * (float)v1[d] +
                      p2 * (float)v2[d] + p3 * (float)v3[d];
    }
    for (; i < end; ++i) {
        int s0 = esrc[i];
        float e0 = alpha_s[s0 * NHEAD + h] + ad;
        half8 v0 = *reinterpret_cast<const half8*>(xh + (size_t)s0 * HHD + l * 8);
        e0 = (e0 > 0.f) ? e0 : NEG_SLOPE * e0;
        float p0 = __expf(e0);
        ssum += p0;
        #pragma unroll
        for (int d = 0; d < 8; ++d)
            acc[d] += p0 * (float)v0[d];
    }
    float inv = 1.f / ssum;
    float4 b0 = *reinterpret_cast<const float4*>(bias + l * 8);
    float4 b1 = *reinterpret_cast<const float4*>(bias + l * 8 + 4);
    float bb[8] = {b0.x, b0.y, b0.z, b0.w, b1.x, b1.y, b1.z, b1.w};
    half8 r;
    #pragma unroll
    for (int d = 0; d < 8; ++d)
        r[d] = (_Float16)fmaxf(acc[d] * inv + bb[d], 0.f);

    if constexpr (!FUSE_CLS) {
        *reinterpret_cast<half8*>(out_h + (size_t)node * HHD + l * 8) = r;
    } else {
        int ln = threadIdx.x >> 5;                 // local node in [0,8)
        *reinterpret_cast<half8*>(&sh[ln][l * 8]) = r;
        __syncthreads();
        // 8 nodes x 64 (class padded) = 512 dots; 2 per thread; c<40 valid
        #pragma unroll
        for (int q = 0; q < 2; ++q) {
            int idx = threadIdx.x + q * 256;
            int lnn = idx >> 6, c = idx & 63;
            if (c < NCLS) {
                const half8* row = reinterpret_cast<const half8*>(&sh[lnn][0]);
                const half8* wrow = reinterpret_cast<const half8*>(WcT + (size_t)c * HHD);
                float s = 0.f;
                #pragma unroll
                for (int j = 0; j < HHD / 8; ++j) {
                    half8 a = row[j], w = wrow[j];
                    #pragma unroll
                    for (int d = 0; d < 8; ++d)
                        s += (float)a[d] * (float)w[d];
                }
                int gnode = blockIdx.x * 8 + lnn;
                out_f[(size_t)gnode * NCLS + c] = s + bc[c];
            }
        }
    }
}

// ---------------- launch ----------------

extern "C" void kernel_launch(void* const* d_in, const int* in_sizes, int n_in,
                              void* d_out, int out_size, void* d_ws, size_t ws_size,
                              hipStream_t stream) {
    const float* x   = (const float*)d_in[0];
    const int*   ei  = (const int*)  d_in[1];
    const float* W1  = (const float*)d_in[2];
    const float* a1s = (const float*)d_in[3];
    const float* a1d = (const float*)d_in[4];
    const float* b1  = (const float*)d_in[5];
    const float* W2  = (const float*)d_in[6];
    const float* a2s = (const float*)d_in[7];
    const float* a2d = (const float*)d_in[8];
    const float* b2  = (const float*)d_in[9];
    const float* Wc  = (const float*)d_in[10];
    const float* bc  = (const float*)d_in[11];
    float* out = (float*)d_out;

    char* ws = (char*)d_ws;
    size_t off = 0;
    auto alloc = [&](size_t bytes) -> void* {
        void* p = ws + off;
        off += (bytes + 255) & ~(size_t)255;
        return p;
    };
    _Float16* xh_h   = (_Float16*)alloc((size_t)NNODES * HHD * 2);
    _Float16* hbuf_h = (_Float16*)alloc((size_t)NNODES * HHD * 2);
    float* as_   = (float*)alloc((size_t)NNODES * NHEAD * 4);
    float* ad_   = (float*)alloc((size_t)NNODES * NHEAD * 4);
    int* counts  = (int*)alloc((size_t)NNODES * 4);
    int* row_ptr = (int*)alloc((size_t)(NNODES + 1) * 4);
    int* cursor  = (int*)alloc((size_t)NNODES * 4);
    int* esrc    = (int*)alloc((size_t)NTOT * 4);
    int* bsums   = (int*)alloc(256 * 4);
    int* boff    = (int*)alloc(256 * 4);
    _Float16* w1t = (_Float16*)alloc((size_t)64 * 64 * 8 * 2);    // 64 frags
    _Float16* w2t = (_Float16*)alloc((size_t)128 * 64 * 8 * 2);   // 128 frags
    _Float16* wcT = (_Float16*)alloc((size_t)NCLS * HHD * 2);     // [40][256]
    (void)ws_size; (void)in_sizes; (void)n_in; (void)out_size;

    int gn = (NNODES + 255) / 256;
    int ge = (NEDGES + 255) / 256;
    int gt = (NTOT + 255) / 256;

    // CSR build (same graph for both layers)
    k_init_counts<<<gn, 256, 0, stream>>>(counts);
    k_count<<<ge, 256, 0, stream>>>(ei, counts);
    k_scan1<<<gn, 256, 0, stream>>>(counts, row_ptr, bsums);
    k_scan2<<<1, 256, 0, stream>>>(bsums, boff, gn);
    k_scan3<<<gn, 256, 0, stream>>>(row_ptr, boff, cursor);
    k_scatter<<<gt, 256, 0, stream>>>(ei, cursor, esrc);

    // weight prep (fragments + WcT)
    k_prep_all<<<(192 * 64 + NCLS * HHD + 255) / 256, 256, 0, stream>>>(
        W1, W2, Wc, w1t, w2t, wcT);

    dim3 gHid(HHD / TBN, (NNODES + TBM - 1) / TBM);   // (2, 391)
    int gagg = NNODES / 8;            // 8 nodes/block (2 per wave)

    // layer 1 (GEMM + fused alpha)
    k_mfma_gemm<float><<<gHid, 256, 0, stream>>>(
        x, w1t, xh_h, a1s, a1d, as_, ad_, NNODES, 128, HHD);
    k_agg<false><<<gagg, 256, 0, stream>>>(xh_h, as_, ad_, row_ptr, esrc, b1,
                                           hbuf_h, nullptr, nullptr, nullptr);

    // layer 2 (GEMM + fused alpha)
    k_mfma_gemm<_Float16><<<gHid, 256, 0, stream>>>(
        hbuf_h, w2t, xh_h, a2s, a2d, as_, ad_, NNODES, HHD, HHD);
    // aggregation + LDS-mediated classifier (writes final output directly)
    k_agg<true><<<gagg, 256, 0, stream>>>(xh_h, as_, ad_, row_ptr, esrc, b2,
                                          nullptr, wcT, bc, out);
}

// Round 14
// 329.126 us; speedup vs baseline: 1.2945x; 1.2945x over previous
//
#include <hip/hip_runtime.h>
#include <math.h>

#define NNODES 50000
#define NEDGES 800000
#define NTOT   850000   // edges + self-loops
#define NHEAD  8
#define HDIM   32
#define HHD    256      // NHEAD*HDIM
#define NCLS   40
#define NEG_SLOPE 0.2f

typedef _Float16 half4 __attribute__((ext_vector_type(4)));
typedef _Float16 half8 __attribute__((ext_vector_type(8)));
typedef float f32x16 __attribute__((ext_vector_type(16)));
typedef unsigned short u16;

// ---------------- CSR build ----------------

__global__ void k_init_counts(int* __restrict__ counts) {
    int i = blockIdx.x * 256 + threadIdx.x;
    if (i < NNODES) counts[i] = 1;   // self-loop
}

__global__ void k_count(const int* __restrict__ ei, int* __restrict__ counts) {
    int i = blockIdx.x * 256 + threadIdx.x;
    if (i < NEDGES) atomicAdd(&counts[ei[NEDGES + i]], 1);  // dst row
}

__global__ __launch_bounds__(256) void k_scan1(const int* __restrict__ counts,
                                               int* __restrict__ partial,
                                               int* __restrict__ bsums) {
    __shared__ int lds[256];
    int t = threadIdx.x;
    int i = blockIdx.x * 256 + t;
    int v = (i < NNODES) ? counts[i] : 0;
    lds[t] = v;
    __syncthreads();
    for (int off = 1; off < 256; off <<= 1) {
        int add = (t >= off) ? lds[t - off] : 0;
        __syncthreads();
        lds[t] += add;
        __syncthreads();
    }
    if (i < NNODES) partial[i] = lds[t] - v;   // exclusive within block
    if (t == 255) bsums[blockIdx.x] = lds[255];
}

__global__ __launch_bounds__(256) void k_scan2(const int* __restrict__ bsums,
                                               int* __restrict__ boff, int nb) {
    __shared__ int lds[256];
    int t = threadIdx.x;
    int v = (t < nb) ? bsums[t] : 0;
    lds[t] = v;
    __syncthreads();
    for (int off = 1; off < 256; off <<= 1) {
        int add = (t >= off) ? lds[t - off] : 0;
        __syncthreads();
        lds[t] += add;
        __syncthreads();
    }
    if (t < nb) boff[t] = lds[t] - v;
}

__global__ void k_scan3(int* __restrict__ row_ptr, const int* __restrict__ boff,
                        int* __restrict__ cursor) {
    int i = blockIdx.x * 256 + threadIdx.x;
    if (i < NNODES) {
        int r = row_ptr[i] + boff[blockIdx.x];
        row_ptr[i] = r;
        cursor[i] = r;
    }
    if (i == 0) row_ptr[NNODES] = NTOT;
}

// fused: regular edges + self-loops
__global__ void k_scatter(const int* __restrict__ ei, int* __restrict__ cursor,
                          int* __restrict__ esrc) {
    int i = blockIdx.x * 256 + threadIdx.x;
    if (i < NEDGES) {
        int s = ei[i];
        int d = ei[NEDGES + i];
        int pos = atomicAdd(&cursor[d], 1);
        esrc[pos] = s;
    } else if (i < NTOT) {
        int n = i - NEDGES;
        int pos = atomicAdd(&cursor[n], 1);
        esrc[pos] = n;
    }
}

// ---------------- weight prep: all three weights, MFMA fragment layout -----
// frag f=(fn,fk); lane l holds 8 halves of col n=fn*32+(l&31),
// rows k=fk*16+((l>>5)<<3)+j. 1 KB contiguous per frag.
__global__ void k_prep_all(const float* __restrict__ W1, const float* __restrict__ W2,
                           const float* __restrict__ Wc,
                           _Float16* __restrict__ w1t, _Float16* __restrict__ w2t,
                           _Float16* __restrict__ wct) {
    int gid = blockIdx.x * 256 + threadIdx.x;   // 256 frags x 64 lanes
    if (gid >= 256 * 64) return;
    int frag = gid >> 6, l = gid & 63;
    const float* W; _Float16* Wt; int K, Nc, fkn, fbase;
    if (frag < 64)       { W = W1; Wt = w1t; K = 128; Nc = 256; fkn = 8;  fbase = 0; }
    else if (frag < 192) { W = W2; Wt = w2t; K = 256; Nc = 256; fkn = 16; fbase = 64; }
    else                 { W = Wc; Wt = wct; K = 256; Nc = 40;  fkn = 16; fbase = 192; }
    int f = frag - fbase;
    int fn = f / fkn, fk = f - fn * fkn;
    int n = fn * 32 + (l & 31);
    int k = fk * 16 + ((l >> 5) << 3);
    half8 v;
    #pragma unroll
    for (int j = 0; j < 8; ++j)
        v[j] = (n < Nc) ? (_Float16)W[(size_t)(k + j) * Nc + n] : (_Float16)0.f;
    *reinterpret_cast<half8*>(Wt + ((size_t)f * 64 + l) * 8) = v;
}

// ---------------- MFMA f16 GEMM (K compile-time; B reg-double-buffered) ----
// MODE 0 (hidden): fp16 C out + LDS-Ct alpha epilogue (known-good R9 form).
// MODE 1 (classifier): fp32 C + bias, cols < NCLS.
#define TBM 128
#define TBN 128
#define TBK 32
#define APAD 34   // 68 B row stride = 17 banks (odd) -> conflict-free b128

template <typename AT, int K, int MODE>
__global__ __launch_bounds__(256) void k_mfma_gemm(
    const AT* __restrict__ A,
    const _Float16* __restrict__ Wt,   // fragment-packed
    _Float16* __restrict__ Ch,
    float* __restrict__ Cf,
    const float* __restrict__ bias,
    const float* __restrict__ a_src,   // [8][32] (MODE 0)
    const float* __restrict__ a_dst,
    float* __restrict__ alpha_s,       // [N][8]
    float* __restrict__ alpha_d,
    int M, int ldc)
{
    constexpr bool A_IS_F32 = sizeof(AT) == 4;
    __shared__ _Float16 Ah[TBM][APAD];
    __shared__ _Float16 Ct[(MODE == 0) ? TBM : 1][TBN + 4];
    int t = threadIdx.x;
    int lane = t & 63;
    int wid = t >> 6;
    int wr = wid >> 1, wc = wid & 1;            // 2x2 wave grid
    int rowBase = blockIdx.y * TBM;
    int colBase = blockIdx.x * TBN;

    int arow = t >> 1;
    int akoff = (t & 1) * 16;
    bool arow_ok = (rowBase + arow) < M;
    const AT* aptr = A + (size_t)(rowBase + arow) * K + akoff;

    constexpr int FKN = K >> 4;   // frags per n-tile row
    size_t bbase[2];
    #pragma unroll
    for (int ct = 0; ct < 2; ++ct) {
        int fn = blockIdx.x * 4 + wc * 2 + ct;
        bbase[ct] = ((size_t)fn * FKN) * 512 + (size_t)lane * 8;
    }

    f32x16 acc[2][2];
    #pragma unroll
    for (int i = 0; i < 2; ++i)
        #pragma unroll
        for (int j = 0; j < 2; ++j)
            #pragma unroll
            for (int r = 0; r < 16; ++r) acc[i][j][r] = 0.f;

    float4 aregf[4];
    half8  aregh[2];
    auto load_a = [&](const AT* ap) {
        if constexpr (A_IS_F32) {
            #pragma unroll
            for (int i = 0; i < 4; ++i)
                aregf[i] = arow_ok ? *reinterpret_cast<const float4*>((const float*)ap + i * 4)
                                   : float4{0.f, 0.f, 0.f, 0.f};
        } else {
            #pragma unroll
            for (int i = 0; i < 2; ++i)
                aregh[i] = arow_ok ? *reinterpret_cast<const half8*>((const _Float16*)ap + i * 8)
                                   : half8{0, 0, 0, 0, 0, 0, 0, 0};
        }
    };
    load_a(aptr);

    // B fragment register double-buffer (current pair bf0/bf1, next bn0/bn1)
    half8 bf0[2], bf1[2];
    #pragma unroll
    for (int ct = 0; ct < 2; ++ct) {
        bf0[ct] = *reinterpret_cast<const half8*>(Wt + bbase[ct]);
        bf1[ct] = *reinterpret_cast<const half8*>(Wt + bbase[ct] + 512);
    }

    #pragma unroll
    for (int k0 = 0; k0 < K; k0 += TBK) {
        if constexpr (A_IS_F32) {
            half8 h0, h1;
            #pragma unroll
            for (int c = 0; c < 4; ++c) {
                float4 v = aregf[c];
                if (c < 2) {
                    h0[c * 4 + 0] = (_Float16)v.x; h0[c * 4 + 1] = (_Float16)v.y;
                    h0[c * 4 + 2] = (_Float16)v.z; h0[c * 4 + 3] = (_Float16)v.w;
                } else {
                    h1[(c - 2) * 4 + 0] = (_Float16)v.x; h1[(c - 2) * 4 + 1] = (_Float16)v.y;
                    h1[(c - 2) * 4 + 2] = (_Float16)v.z; h1[(c - 2) * 4 + 3] = (_Float16)v.w;
                }
            }
            *reinterpret_cast<half8*>(&Ah[arow][akoff])     = h0;
            *reinterpret_cast<half8*>(&Ah[arow][akoff + 8]) = h1;
        } else {
            *reinterpret_cast<half8*>(&Ah[arow][akoff])     = aregh[0];
            *reinterpret_cast<half8*>(&Ah[arow][akoff + 8]) = aregh[1];
        }
        __syncthreads();
        if (k0 + TBK < K) load_a(aptr + k0 + TBK);
        half8 bn0[2], bn1[2];
        if (k0 + TBK < K) {
            #pragma unroll
            for (int ct = 0; ct < 2; ++ct) {
                size_t nb = bbase[ct] + (size_t)((k0 >> 4) + 2) * 512;
                bn0[ct] = *reinterpret_cast<const half8*>(Wt + nb);
                bn1[ct] = *reinterpret_cast<const half8*>(Wt + nb + 512);
            }
        }
        #pragma unroll
        for (int sub = 0; sub < 2; ++sub) {
            int kfo = sub * 16 + (lane >> 5) * 8;
            half8 ah[2];
            #pragma unroll
            for (int rt = 0; rt < 2; ++rt) {
                int r = wr * 64 + rt * 32 + (lane & 31);
                ah[rt] = *reinterpret_cast<const half8*>(&Ah[r][kfo]);
            }
            #pragma unroll
            for (int rt = 0; rt < 2; ++rt)
                #pragma unroll
                for (int ct = 0; ct < 2; ++ct)
                    acc[rt][ct] = __builtin_amdgcn_mfma_f32_32x32x16_f16(
                        ah[rt], (sub == 0) ? bf0[ct] : bf1[ct], acc[rt][ct], 0, 0, 0);
        }
        if (k0 + TBK < K) {
            #pragma unroll
            for (int ct = 0; ct < 2; ++ct) { bf0[ct] = bn0[ct]; bf1[ct] = bn1[ct]; }
        }
        __syncthreads();
    }

    // ---- C store (+ LDS stage for MODE 0) ----
    #pragma unroll
    for (int rt = 0; rt < 2; ++rt)
        #pragma unroll
        for (int ct = 0; ct < 2; ++ct) {
            int lcol = wc * 64 + ct * 32 + (lane & 31);
            int col = colBase + lcol;
            #pragma unroll
            for (int r = 0; r < 16; ++r) {
                int lrow = wr * 64 + rt * 32 + (r & 3) + 8 * (r >> 2) + 4 * (lane >> 5);
                int row = rowBase + lrow;
                float v = acc[rt][ct][r];
                if constexpr (MODE == 0) {
                    _Float16 hv = (_Float16)v;
                    Ct[lrow][lcol] = hv;
                    if (row < M)
                        Ch[(size_t)row * ldc + col] = hv;
                } else {
                    if (row < M && col < NCLS)
                        Cf[(size_t)row * ldc + col] = v + bias[col];
                }
            }
        }

    if constexpr (MODE == 0) {
        __syncthreads();
        // 128 rows x 4 heads = 512 (row, head) pairs; 2 per thread
        #pragma unroll
        for (int idx = t; idx < TBM * 4; idx += 256) {
            int lrow = idx >> 2, hoff = idx & 3;
            int grow = rowBase + lrow;
            if (grow < M) {
                int h = blockIdx.x * 4 + hoff;
                const float* as4 = a_src + h * HDIM;
                const float* ad4 = a_dst + h * HDIM;
                float ss = 0.f, sd = 0.f;
                #pragma unroll
                for (int j = 0; j < HDIM; ++j) {
                    float v = (float)Ct[lrow][hoff * 32 + j];
                    ss += v * as4[j];
                    sd += v * ad4[j];
                }
                alpha_s[grow * NHEAD + h] = ss;
                alpha_d[grow * NHEAD + h] = sd;
            }
        }
    }
}

// ---------------- GAT aggregation: fused single-pass softmax + gather ------
// 2 nodes per wave; lane l in [0,32) covers dims [8l, 8l+8) via one half8.
// No max-subtraction: e is a small-scale dot (|e| << 80), exp cannot overflow.
// Manual 4-way unroll for memory-level parallelism (4 gathers in flight).
__global__ __launch_bounds__(256) void k_agg(const _Float16* __restrict__ xh,
                                             const float* __restrict__ alpha_s,
                                             const float* __restrict__ alpha_d,
                                             const int* __restrict__ row_ptr,
                                             const int* __restrict__ esrc,
                                             const float* __restrict__ bias,
                                             _Float16* __restrict__ out) {
    int wave = blockIdx.x * 4 + (threadIdx.x >> 6);
    int node = wave * 2 + ((threadIdx.x & 63) >> 5);
    if (node >= NNODES) return;
    int l = threadIdx.x & 31;        // dim chunk [8l, 8l+8)
    int h = l >> 2;                  // head of this chunk
    int beg = row_ptr[node], end = row_ptr[node + 1];
    float ad = alpha_d[node * NHEAD + h];
    float acc[8] = {};
    float ssum = 0.f;
    int i = beg;
    for (; i + 3 < end; i += 4) {
        int s0 = esrc[i], s1 = esrc[i + 1], s2 = esrc[i + 2], s3 = esrc[i + 3];
        float e0 = alpha_s[s0 * NHEAD + h] + ad;
        float e1 = alpha_s[s1 * NHEAD + h] + ad;
        float e2 = alpha_s[s2 * NHEAD + h] + ad;
        float e3 = alpha_s[s3 * NHEAD + h] + ad;
        half8 v0 = *reinterpret_cast<const half8*>(xh + (size_t)s0 * HHD + l * 8);
        half8 v1 = *reinterpret_cast<const half8*>(xh + (size_t)s1 * HHD + l * 8);
        half8 v2 = *reinterpret_cast<const half8*>(xh + (size_t)s2 * HHD + l * 8);
        half8 v3 = *reinterpret_cast<const half8*>(xh + (size_t)s3 * HHD + l * 8);
        e0 = (e0 > 0.f) ? e0 : NEG_SLOPE * e0;
        e1 = (e1 > 0.f) ? e1 : NEG_SLOPE * e1;
        e2 = (e2 > 0.f) ? e2 : NEG_SLOPE * e2;
        e3 = (e3 > 0.f) ? e3 : NEG_SLOPE * e3;
        float p0 = __expf(e0), p1 = __expf(e1), p2 = __expf(e2), p3 = __expf(e3);
        ssum += (p0 + p1) + (p2 + p3);
        #pragma unroll
        for (int d = 0; d < 8; ++d)
            acc[d] += p0 * (float)v0[d] + p1 * (float)v1[d] +
                      p2 * (float)v2[d] + p3 * (float)v3[d];
    }
    for (; i < end; ++i) {
        int s0 = esrc[i];
        float e0 = alpha_s[s0 * NHEAD + h] + ad;
        half8 v0 = *reinterpret_cast<const half8*>(xh + (size_t)s0 * HHD + l * 8);
        e0 = (e0 > 0.f) ? e0 : NEG_SLOPE * e0;
        float p0 = __expf(e0);
        ssum += p0;
        #pragma unroll
        for (int d = 0; d < 8; ++d)
            acc[d] += p0 * (float)v0[d];
    }
    float inv = 1.f / ssum;
    float4 b0 = *reinterpret_cast<const float4*>(bias + l * 8);
    float4 b1 = *reinterpret_cast<const float4*>(bias + l * 8 + 4);
    float bb[8] = {b0.x, b0.y, b0.z, b0.w, b1.x, b1.y, b1.z, b1.w};
    half8 r;
    #pragma unroll
    for (int d = 0; d < 8; ++d)
        r[d] = (_Float16)fmaxf(acc[d] * inv + bb[d], 0.f);
    *reinterpret_cast<half8*>(out + (size_t)node * HHD + l * 8) = r;
}

// ---------------- launch ----------------

extern "C" void kernel_launch(void* const* d_in, const int* in_sizes, int n_in,
                              void* d_out, int out_size, void* d_ws, size_t ws_size,
                              hipStream_t stream) {
    const float* x   = (const float*)d_in[0];
    const int*   ei  = (const int*)  d_in[1];
    const float* W1  = (const float*)d_in[2];
    const float* a1s = (const float*)d_in[3];
    const float* a1d = (const float*)d_in[4];
    const float* b1  = (const float*)d_in[5];
    const float* W2  = (const float*)d_in[6];
    const float* a2s = (const float*)d_in[7];
    const float* a2d = (const float*)d_in[8];
    const float* b2  = (const float*)d_in[9];
    const float* Wc  = (const float*)d_in[10];
    const float* bc  = (const float*)d_in[11];
    float* out = (float*)d_out;

    char* ws = (char*)d_ws;
    size_t off = 0;
    auto alloc = [&](size_t bytes) -> void* {
        void* p = ws + off;
        off += (bytes + 255) & ~(size_t)255;
        return p;
    };
    _Float16* xh_h   = (_Float16*)alloc((size_t)NNODES * HHD * 2);
    _Float16* hbuf_h = (_Float16*)alloc((size_t)NNODES * HHD * 2);
    float* as_   = (float*)alloc((size_t)NNODES * NHEAD * 4);
    float* ad_   = (float*)alloc((size_t)NNODES * NHEAD * 4);
    int* counts  = (int*)alloc((size_t)NNODES * 4);
    int* row_ptr = (int*)alloc((size_t)(NNODES + 1) * 4);
    int* cursor  = (int*)alloc((size_t)NNODES * 4);
    int* esrc    = (int*)alloc((size_t)NTOT * 4);
    int* bsums   = (int*)alloc(256 * 4);
    int* boff    = (int*)alloc(256 * 4);
    _Float16* w1t = (_Float16*)alloc((size_t)64 * 64 * 8 * 2);    // 64 frags
    _Float16* w2t = (_Float16*)alloc((size_t)128 * 64 * 8 * 2);   // 128 frags
    _Float16* wct = (_Float16*)alloc((size_t)64 * 64 * 8 * 2);    // 64 frags
    (void)ws_size; (void)in_sizes; (void)n_in; (void)out_size;

    int gn = (NNODES + 255) / 256;
    int ge = (NEDGES + 255) / 256;
    int gt = (NTOT + 255) / 256;

    // CSR build (same graph for both layers)
    k_init_counts<<<gn, 256, 0, stream>>>(counts);
    k_count<<<ge, 256, 0, stream>>>(ei, counts);
    k_scan1<<<gn, 256, 0, stream>>>(counts, row_ptr, bsums);
    k_scan2<<<1, 256, 0, stream>>>(bsums, boff, gn);
    k_scan3<<<gn, 256, 0, stream>>>(row_ptr, boff, cursor);
    k_scatter<<<gt, 256, 0, stream>>>(ei, cursor, esrc);

    // weight prep (fragment pack, all three)
    k_prep_all<<<64, 256, 0, stream>>>(W1, W2, Wc, w1t, w2t, wct);

    dim3 gHid(HHD / TBN, (NNODES + TBM - 1) / TBM);   // (2, 391)
    dim3 gCls(1, (NNODES + TBM - 1) / TBM);           // (1, 391)
    int gagg = NNODES / 8;            // 8 nodes/block (2 per wave)

    // layer 1 (GEMM + fused alpha)
    k_mfma_gemm<float, 128, 0><<<gHid, 256, 0, stream>>>(
        x, w1t, xh_h, nullptr, nullptr, a1s, a1d, as_, ad_, NNODES, HHD);
    k_agg<<<gagg, 256, 0, stream>>>(xh_h, as_, ad_, row_ptr, esrc, b1, hbuf_h);

    // layer 2 (GEMM + fused alpha)
    k_mfma_gemm<_Float16, 256, 0><<<gHid, 256, 0, stream>>>(
        hbuf_h, w2t, xh_h, nullptr, nullptr, a2s, a2d, as_, ad_, NNODES, HHD);
    k_agg<<<gagg, 256, 0, stream>>>(xh_h, as_, ad_, row_ptr, esrc, b2, hbuf_h);

    // classifier
    k_mfma_gemm<_Float16, 256, 1><<<gCls, 256, 0, stream>>>(
        hbuf_h, wct, nullptr, out, bc, nullptr, nullptr, nullptr, nullptr,
        NNODES, NCLS);
}

// Round 15
// 311.702 us; speedup vs baseline: 1.3669x; 1.0559x over previous
//
#include <hip/hip_runtime.h>
#include <math.h>

#define NNODES 50000
#define NEDGES 800000
#define NTOT   850000   // edges + self-loops
#define NHEAD  8
#define HDIM   32
#define HHD    256      // NHEAD*HDIM
#define NCLS   40
#define NEG_SLOPE 0.2f

typedef _Float16 half4 __attribute__((ext_vector_type(4)));
typedef _Float16 half8 __attribute__((ext_vector_type(8)));
typedef float f32x16 __attribute__((ext_vector_type(16)));
typedef unsigned short u16;

// ---------------- CSR build ----------------

__global__ void k_init_counts(int* __restrict__ counts) {
    int i = blockIdx.x * 256 + threadIdx.x;
    if (i < NNODES) counts[i] = 1;   // self-loop
}

__global__ void k_count(const int* __restrict__ ei, int* __restrict__ counts) {
    int i = blockIdx.x * 256 + threadIdx.x;
    if (i < NEDGES) atomicAdd(&counts[ei[NEDGES + i]], 1);  // dst row
}

__global__ __launch_bounds__(256) void k_scan1(const int* __restrict__ counts,
                                               int* __restrict__ partial,
                                               int* __restrict__ bsums) {
    __shared__ int lds[256];
    int t = threadIdx.x;
    int i = blockIdx.x * 256 + t;
    int v = (i < NNODES) ? counts[i] : 0;
    lds[t] = v;
    __syncthreads();
    for (int off = 1; off < 256; off <<= 1) {
        int add = (t >= off) ? lds[t - off] : 0;
        __syncthreads();
        lds[t] += add;
        __syncthreads();
    }
    if (i < NNODES) partial[i] = lds[t] - v;   // exclusive within block
    if (t == 255) bsums[blockIdx.x] = lds[255];
}

__global__ __launch_bounds__(256) void k_scan2(const int* __restrict__ bsums,
                                               int* __restrict__ boff, int nb) {
    __shared__ int lds[256];
    int t = threadIdx.x;
    int v = (t < nb) ? bsums[t] : 0;
    lds[t] = v;
    __syncthreads();
    for (int off = 1; off < 256; off <<= 1) {
        int add = (t >= off) ? lds[t - off] : 0;
        __syncthreads();
        lds[t] += add;
        __syncthreads();
    }
    if (t < nb) boff[t] = lds[t] - v;
}

__global__ void k_scan3(int* __restrict__ row_ptr, const int* __restrict__ boff,
                        int* __restrict__ cursor) {
    int i = blockIdx.x * 256 + threadIdx.x;
    if (i < NNODES) {
        int r = row_ptr[i] + boff[blockIdx.x];
        row_ptr[i] = r;
        cursor[i] = r;
    }
    if (i == 0) row_ptr[NNODES] = NTOT;
}

// fused: regular edges + self-loops
__global__ void k_scatter(const int* __restrict__ ei, int* __restrict__ cursor,
                          int* __restrict__ esrc) {
    int i = blockIdx.x * 256 + threadIdx.x;
    if (i < NEDGES) {
        int s = ei[i];
        int d = ei[NEDGES + i];
        int pos = atomicAdd(&cursor[d], 1);
        esrc[pos] = s;
    } else if (i < NTOT) {
        int n = i - NEDGES;
        int pos = atomicAdd(&cursor[n], 1);
        esrc[pos] = n;
    }
}

// ---------------- weight prep: all three weights, MFMA fragment layout -----
// frag f=(fn,fk); lane l holds 8 halves of col n=fn*32+(l&31),
// rows k=fk*16+((l>>5)<<3)+j. 1 KB contiguous per frag.
__global__ void k_prep_all(const float* __restrict__ W1, const float* __restrict__ W2,
                           const float* __restrict__ Wc,
                           _Float16* __restrict__ w1t, _Float16* __restrict__ w2t,
                           _Float16* __restrict__ wct) {
    int gid = blockIdx.x * 256 + threadIdx.x;   // 256 frags x 64 lanes
    if (gid >= 256 * 64) return;
    int frag = gid >> 6, l = gid & 63;
    const float* W; _Float16* Wt; int K, Nc, fkn, fbase;
    if (frag < 64)       { W = W1; Wt = w1t; K = 128; Nc = 256; fkn = 8;  fbase = 0; }
    else if (frag < 192) { W = W2; Wt = w2t; K = 256; Nc = 256; fkn = 16; fbase = 64; }
    else                 { W = Wc; Wt = wct; K = 256; Nc = 40;  fkn = 16; fbase = 192; }
    int f = frag - fbase;
    int fn = f / fkn, fk = f - fn * fkn;
    int n = fn * 32 + (l & 31);
    int k = fk * 16 + ((l >> 5) << 3);
    half8 v;
    #pragma unroll
    for (int j = 0; j < 8; ++j)
        v[j] = (n < Nc) ? (_Float16)W[(size_t)(k + j) * Nc + n] : (_Float16)0.f;
    *reinterpret_cast<half8*>(Wt + ((size_t)f * 64 + l) * 8) = v;
}

// ---------------- MFMA f16 GEMM (TBM=64, grid-doubled; LDS union) ----------
// MODE 0 (hidden): fp16 C via LDS-staged Ct + vector write-out, + alpha
//   epilogue from Ct. MODE 1 (classifier): direct fp32 + bias, cols < NCLS.
#define TBM 64
#define TBN 128
#define TBK 32
#define APAD 34    // 68 B row stride (odd banks) -> conflict-free b128
#define LDCT 132   // Ct row stride in halves

template <typename AT, int K, int MODE>
__global__ __launch_bounds__(256) void k_mfma_gemm(
    const AT* __restrict__ A,
    const _Float16* __restrict__ Wt,   // fragment-packed
    _Float16* __restrict__ Ch,
    float* __restrict__ Cf,
    const float* __restrict__ bias,
    const float* __restrict__ a_src,   // [8][32] (MODE 0)
    const float* __restrict__ a_dst,
    float* __restrict__ alpha_s,       // [N][8]
    float* __restrict__ alpha_d,
    int M, int ldc)
{
    constexpr bool A_IS_F32 = sizeof(AT) == 4;
    // union: Ah (64x34) lives during K loop; Ct (64x132) after final barrier
    constexpr int SMEM_ELEMS = (MODE == 0) ? TBM * LDCT : TBM * APAD;
    __shared__ _Float16 smem[SMEM_ELEMS];
    int t = threadIdx.x;
    int lane = t & 63;
    int wid = t >> 6;
    int wr = wid >> 1, wc = wid & 1;            // 2x2 wave grid; wave = 32r x 64c
    int rowBase = blockIdx.y * TBM;
    int colBase = blockIdx.x * TBN;

    int arow = t >> 2;                 // 64 rows, 4 threads/row
    int akoff = (t & 3) * 8;           // 8 elements each
    bool arow_ok = (rowBase + arow) < M;
    const AT* aptr = A + (size_t)(rowBase + arow) * K + akoff;

    constexpr int FKN = K >> 4;   // frags per n-tile row
    size_t bbase[2];
    #pragma unroll
    for (int ct = 0; ct < 2; ++ct) {
        int fn = blockIdx.x * 4 + wc * 2 + ct;
        bbase[ct] = ((size_t)fn * FKN) * 512 + (size_t)lane * 8;
    }

    f32x16 acc[2];
    #pragma unroll
    for (int j = 0; j < 2; ++j)
        #pragma unroll
        for (int r = 0; r < 16; ++r) acc[j][r] = 0.f;

    float4 aregf[2];
    half8  aregh;
    auto load_a = [&](const AT* ap) {
        if constexpr (A_IS_F32) {
            #pragma unroll
            for (int i = 0; i < 2; ++i)
                aregf[i] = arow_ok ? *reinterpret_cast<const float4*>((const float*)ap + i * 4)
                                   : float4{0.f, 0.f, 0.f, 0.f};
        } else {
            aregh = arow_ok ? *reinterpret_cast<const half8*>((const _Float16*)ap)
                            : half8{0, 0, 0, 0, 0, 0, 0, 0};
        }
    };
    load_a(aptr);

    // B fragment register double-buffer
    half8 bf0[2], bf1[2];
    #pragma unroll
    for (int ct = 0; ct < 2; ++ct) {
        bf0[ct] = *reinterpret_cast<const half8*>(Wt + bbase[ct]);
        bf1[ct] = *reinterpret_cast<const half8*>(Wt + bbase[ct] + 512);
    }

    #pragma unroll
    for (int k0 = 0; k0 < K; k0 += TBK) {
        half8 hv;
        if constexpr (A_IS_F32) {
            hv[0] = (_Float16)aregf[0].x; hv[1] = (_Float16)aregf[0].y;
            hv[2] = (_Float16)aregf[0].z; hv[3] = (_Float16)aregf[0].w;
            hv[4] = (_Float16)aregf[1].x; hv[5] = (_Float16)aregf[1].y;
            hv[6] = (_Float16)aregf[1].z; hv[7] = (_Float16)aregf[1].w;
        } else {
            hv = aregh;
        }
        *reinterpret_cast<half8*>(&smem[arow * APAD + akoff]) = hv;
        __syncthreads();
        if (k0 + TBK < K) load_a(aptr + k0 + TBK);
        half8 bn0[2], bn1[2];
        if (k0 + TBK < K) {
            #pragma unroll
            for (int ct = 0; ct < 2; ++ct) {
                size_t nb = bbase[ct] + (size_t)((k0 >> 4) + 2) * 512;
                bn0[ct] = *reinterpret_cast<const half8*>(Wt + nb);
                bn1[ct] = *reinterpret_cast<const half8*>(Wt + nb + 512);
            }
        }
        #pragma unroll
        for (int sub = 0; sub < 2; ++sub) {
            int kfo = sub * 16 + (lane >> 5) * 8;
            half8 ah = *reinterpret_cast<const half8*>(
                &smem[(wr * 32 + (lane & 31)) * APAD + kfo]);
            #pragma unroll
            for (int ct = 0; ct < 2; ++ct)
                acc[ct] = __builtin_amdgcn_mfma_f32_32x32x16_f16(
                    ah, (sub == 0) ? bf0[ct] : bf1[ct], acc[ct], 0, 0, 0);
        }
        if (k0 + TBK < K) {
            #pragma unroll
            for (int ct = 0; ct < 2; ++ct) { bf0[ct] = bn0[ct]; bf1[ct] = bn1[ct]; }
        }
        __syncthreads();
    }
    // after this barrier Ah is dead -> smem reused as Ct (MODE 0)

    if constexpr (MODE == 0) {
        // acc -> Ct (scalar LDS stores; C-layout transpose)
        #pragma unroll
        for (int ct = 0; ct < 2; ++ct) {
            int lcol = wc * 64 + ct * 32 + (lane & 31);
            #pragma unroll
            for (int r = 0; r < 16; ++r) {
                int lrow = wr * 32 + (r & 3) + 8 * (r >> 2) + 4 * (lane >> 5);
                smem[lrow * LDCT + lcol] = (_Float16)acc[ct][r];
            }
        }
        __syncthreads();
        // vectorized C write: 64 rows x 16 col-chunks (half8) = 4 passes
        #pragma unroll
        for (int pass = 0; pass < 4; ++pass) {
            int idx = t + pass * 256;
            int lrow = idx >> 4;
            int cchunk = (idx & 15) * 8;
            int grow = rowBase + lrow;
            if (grow < M) {
                half8 v = *reinterpret_cast<const half8*>(&smem[lrow * LDCT + cchunk]);
                *reinterpret_cast<half8*>(Ch + (size_t)grow * ldc + colBase + cchunk) = v;
            }
        }
        // alpha epilogue: 64 rows x 4 heads = 256 pairs, 1 per thread
        {
            int lrow = t >> 2, hoff = t & 3;
            int grow = rowBase + lrow;
            if (grow < M) {
                int h = blockIdx.x * 4 + hoff;
                const float* as4 = a_src + h * HDIM;
                const float* ad4 = a_dst + h * HDIM;
                float ss = 0.f, sd = 0.f;
                #pragma unroll
                for (int j = 0; j < HDIM; ++j) {
                    float v = (float)smem[lrow * LDCT + hoff * 32 + j];
                    ss += v * as4[j];
                    sd += v * ad4[j];
                }
                alpha_s[grow * NHEAD + h] = ss;
                alpha_d[grow * NHEAD + h] = sd;
            }
        }
    } else {
        // classifier: direct fp32 + bias, cols < NCLS
        #pragma unroll
        for (int ct = 0; ct < 2; ++ct) {
            int col = colBase + wc * 64 + ct * 32 + (lane & 31);
            #pragma unroll
            for (int r = 0; r < 16; ++r) {
                int row = rowBase + wr * 32 + (r & 3) + 8 * (r >> 2) + 4 * (lane >> 5);
                if (row < M && col < NCLS)
                    Cf[(size_t)row * ldc + col] = acc[ct][r] + bias[col];
            }
        }
    }
}

// ---------------- GAT aggregation: fused single-pass softmax + gather ------
// 2 nodes per wave; lane l in [0,32) covers dims [8l, 8l+8) via one half8.
// No max-subtraction: e is a small-scale dot (|e| << 80), exp cannot overflow.
// Manual 4-way unroll for memory-level parallelism (4 gathers in flight).
__global__ __launch_bounds__(256) void k_agg(const _Float16* __restrict__ xh,
                                             const float* __restrict__ alpha_s,
                                             const float* __restrict__ alpha_d,
                                             const int* __restrict__ row_ptr,
                                             const int* __restrict__ esrc,
                                             const float* __restrict__ bias,
                                             _Float16* __restrict__ out) {
    int wave = blockIdx.x * 4 + (threadIdx.x >> 6);
    int node = wave * 2 + ((threadIdx.x & 63) >> 5);
    if (node >= NNODES) return;
    int l = threadIdx.x & 31;        // dim chunk [8l, 8l+8)
    int h = l >> 2;                  // head of this chunk
    int beg = row_ptr[node], end = row_ptr[node + 1];
    float ad = alpha_d[node * NHEAD + h];
    float acc[8] = {};
    float ssum = 0.f;
    int i = beg;
    for (; i + 3 < end; i += 4) {
        int s0 = esrc[i], s1 = esrc[i + 1], s2 = esrc[i + 2], s3 = esrc[i + 3];
        float e0 = alpha_s[s0 * NHEAD + h] + ad;
        float e1 = alpha_s[s1 * NHEAD + h] + ad;
        float e2 = alpha_s[s2 * NHEAD + h] + ad;
        float e3 = alpha_s[s3 * NHEAD + h] + ad;
        half8 v0 = *reinterpret_cast<const half8*>(xh + (size_t)s0 * HHD + l * 8);
        half8 v1 = *reinterpret_cast<const half8*>(xh + (size_t)s1 * HHD + l * 8);
        half8 v2 = *reinterpret_cast<const half8*>(xh + (size_t)s2 * HHD + l * 8);
        half8 v3 = *reinterpret_cast<const half8*>(xh + (size_t)s3 * HHD + l * 8);
        e0 = (e0 > 0.f) ? e0 : NEG_SLOPE * e0;
        e1 = (e1 > 0.f) ? e1 : NEG_SLOPE * e1;
        e2 = (e2 > 0.f) ? e2 : NEG_SLOPE * e2;
        e3 = (e3 > 0.f) ? e3 : NEG_SLOPE * e3;
        float p0 = __expf(e0), p1 = __expf(e1), p2 = __expf(e2), p3 = __expf(e3);
        ssum += (p0 + p1) + (p2 + p3);
        #pragma unroll
        for (int d = 0; d < 8; ++d)
            acc[d] += p0 * (float)v0[d] + p1 * (float)v1[d] +
                      p2 * (float)v2[d] + p3 * (float)v3[d];
    }
    for (; i < end; ++i) {
        int s0 = esrc[i];
        float e0 = alpha_s[s0 * NHEAD + h] + ad;
        half8 v0 = *reinterpret_cast<const half8*>(xh + (size_t)s0 * HHD + l * 8);
        e0 = (e0 > 0.f) ? e0 : NEG_SLOPE * e0;
        float p0 = __expf(e0);
        ssum += p0;
        #pragma unroll
        for (int d = 0; d < 8; ++d)
            acc[d] += p0 * (float)v0[d];
    }
    float inv = 1.f / ssum;
    float4 b0 = *reinterpret_cast<const float4*>(bias + l * 8);
    float4 b1 = *reinterpret_cast<const float4*>(bias + l * 8 + 4);
    float bb[8] = {b0.x, b0.y, b0.z, b0.w, b1.x, b1.y, b1.z, b1.w};
    half8 r;
    #pragma unroll
    for (int d = 0; d < 8; ++d)
        r[d] = (_Float16)fmaxf(acc[d] * inv + bb[d], 0.f);
    *reinterpret_cast<half8*>(out + (size_t)node * HHD + l * 8) = r;
}

// ---------------- launch ----------------

extern "C" void kernel_launch(void* const* d_in, const int* in_sizes, int n_in,
                              void* d_out, int out_size, void* d_ws, size_t ws_size,
                              hipStream_t stream) {
    const float* x   = (const float*)d_in[0];
    const int*   ei  = (const int*)  d_in[1];
    const float* W1  = (const float*)d_in[2];
    const float* a1s = (const float*)d_in[3];
    const float* a1d = (const float*)d_in[4];
    const float* b1  = (const float*)d_in[5];
    const float* W2  = (const float*)d_in[6];
    const float* a2s = (const float*)d_in[7];
    const float* a2d = (const float*)d_in[8];
    const float* b2  = (const float*)d_in[9];
    const float* Wc  = (const float*)d_in[10];
    const float* bc  = (const float*)d_in[11];
    float* out = (float*)d_out;

    char* ws = (char*)d_ws;
    size_t off = 0;
    auto alloc = [&](size_t bytes) -> void* {
        void* p = ws + off;
        off += (bytes + 255) & ~(size_t)255;
        return p;
    };
    _Float16* xh_h   = (_Float16*)alloc((size_t)NNODES * HHD * 2);
    _Float16* hbuf_h = (_Float16*)alloc((size_t)NNODES * HHD * 2);
    float* as_   = (float*)alloc((size_t)NNODES * NHEAD * 4);
    float* ad_   = (float*)alloc((size_t)NNODES * NHEAD * 4);
    int* counts  = (int*)alloc((size_t)NNODES * 4);
    int* row_ptr = (int*)alloc((size_t)(NNODES + 1) * 4);
    int* cursor  = (int*)alloc((size_t)NNODES * 4);
    int* esrc    = (int*)alloc((size_t)NTOT * 4);
    int* bsums   = (int*)alloc(256 * 4);
    int* boff    = (int*)alloc(256 * 4);
    _Float16* w1t = (_Float16*)alloc((size_t)64 * 64 * 8 * 2);    // 64 frags
    _Float16* w2t = (_Float16*)alloc((size_t)128 * 64 * 8 * 2);   // 128 frags
    _Float16* wct = (_Float16*)alloc((size_t)64 * 64 * 8 * 2);    // 64 frags
    (void)ws_size; (void)in_sizes; (void)n_in; (void)out_size;

    int gn = (NNODES + 255) / 256;
    int ge = (NEDGES + 255) / 256;
    int gt = (NTOT + 255) / 256;

    // CSR build (same graph for both layers)
    k_init_counts<<<gn, 256, 0, stream>>>(counts);
    k_count<<<ge, 256, 0, stream>>>(ei, counts);
    k_scan1<<<gn, 256, 0, stream>>>(counts, row_ptr, bsums);
    k_scan2<<<1, 256, 0, stream>>>(bsums, boff, gn);
    k_scan3<<<gn, 256, 0, stream>>>(row_ptr, boff, cursor);
    k_scatter<<<gt, 256, 0, stream>>>(ei, cursor, esrc);

    // weight prep (fragment pack, all three)
    k_prep_all<<<64, 256, 0, stream>>>(W1, W2, Wc, w1t, w2t, wct);

    dim3 gHid(HHD / TBN, (NNODES + TBM - 1) / TBM);   // (2, 782)
    dim3 gCls(1, (NNODES + TBM - 1) / TBM);           // (1, 782)
    int gagg = NNODES / 8;            // 8 nodes/block (2 per wave)

    // layer 1 (GEMM + fused alpha)
    k_mfma_gemm<float, 128, 0><<<gHid, 256, 0, stream>>>(
        x, w1t, xh_h, nullptr, nullptr, a1s, a1d, as_, ad_, NNODES, HHD);
    k_agg<<<gagg, 256, 0, stream>>>(xh_h, as_, ad_, row_ptr, esrc, b1, hbuf_h);

    // layer 2 (GEMM + fused alpha)
    k_mfma_gemm<_Float16, 256, 0><<<gHid, 256, 0, stream>>>(
        hbuf_h, w2t, xh_h, nullptr, nullptr, a2s, a2d, as_, ad_, NNODES, HHD);
    k_agg<<<gagg, 256, 0, stream>>>(xh_h, as_, ad_, row_ptr, esrc, b2, hbuf_h);

    // classifier
    k_mfma_gemm<_Float16, 256, 1><<<gCls, 256, 0, stream>>>(
        hbuf_h, wct, nullptr, out, bc, nullptr, nullptr, nullptr, nullptr,
        NNODES, NCLS);
}